// Round 11
// baseline (322.395 us; speedup 1.0000x reference)
//
#include <hip/hip_runtime.h>
#include <hip/hip_bf16.h>
#include <stdint.h>

#define NLOG 18
#define NMASK ((1u << NLOG) - 1u)
#define RSTRB 592u  // W row stride bytes = 37 chunks * 16; 148 dwords == 20 mod 32 banks
#define ROWS 128u
#define MPB (ROWS * 286u)  // 36608 w-elements per block

typedef __attribute__((ext_vector_type(8))) short short8;
typedef __attribute__((ext_vector_type(4))) float f32x4;

// ---- compile-time monomial table: nibble-packed (a+1)|(b+1)<<4|(c+1)<<8 ----
struct Tab { uint16_t v[286]; };
constexpr Tab make_tab() {
  Tab t{};
  int idx = 0;
  t.v[idx++] = 0;  // degree 0
  for (int a = 0; a < 10; ++a) t.v[idx++] = (uint16_t)(a + 1);
  for (int a = 0; a < 10; ++a)
    for (int b = a; b < 10; ++b) t.v[idx++] = (uint16_t)((a + 1) | ((b + 1) << 4));
  for (int a = 0; a < 10; ++a)
    for (int b = a; b < 10; ++b)
      for (int c = b; c < 10; ++c)
        t.v[idx++] = (uint16_t)((a + 1) | ((b + 1) << 4) | ((c + 1) << 8));
  return t;
}
__constant__ Tab g_tab = make_tab();

// Packed bf16 B: 9 k-steps x 4 k-octets x 320 e; 16B chunk = M[k0*32+g*8+i][e], i=0..7.
// 184 KB, L2-resident -> read directly in the k-loop (single-buffered; latency covered
// by 20 MFMA/k-step x 4 waves/SIMD = 384 cy > ~200 cy L2 latency).
__device__ uint4 g_bpack[11520];

__device__ __forceinline__ uint32_t f2bf(float f) {
  uint32_t u = __float_as_uint(f);
  return (u + 0x7FFFu + ((u >> 16) & 1u)) >> 16;
}
__device__ __forceinline__ float bf2f(uint32_t u) { return __uint_as_float(u << 16); }
__device__ __forceinline__ uint32_t pk2bf(float lo, float hi) {
  __hip_bfloat162 h2 = __float22bfloat162_rn(make_float2(lo, hi));  // v_cvt_pk_bf16_f32
  return *(uint32_t*)&h2;
}

__global__ __launch_bounds__(256) void prep_kernel(const float* __restrict__ M) {
  uint32_t t = blockIdx.x * 256u + threadIdx.x;  // 0..11519
  uint32_t k0 = t / 1280u;
  uint32_t r = t - k0 * 1280u;
  uint32_t g = r / 320u;
  uint32_t e = r - g * 320u;
  uint32_t kb = k0 * 32u + g * 8u;
  float v[8];
#pragma unroll
  for (int i = 0; i < 8; ++i) {
    uint32_t k = kb + (uint32_t)i;
    v[i] = (k < 286u && e < 286u) ? M[k * 286u + e] : 0.f;
  }
  uint4 o;
  o.x = f2bf(v[0]) | (f2bf(v[1]) << 16);
  o.y = f2bf(v[2]) | (f2bf(v[3]) << 16);
  o.z = f2bf(v[4]) | (f2bf(v[5]) << 16);
  o.w = f2bf(v[6]) | (f2bf(v[7]) << 16);
  g_bpack[t] = o;
}

// Unified VGPR+AGPR budget in the GEMM phase: acc 80 (AGPR) + b 20 + a 4 + addr ~12
// ≈ 116 -> fits the 128-reg tier (512,4). Spill tell = WRITE_SIZE (round-5: 165 MB).
__global__ __launch_bounds__(512, 4) void qform_kernel(const float* __restrict__ x,
                                                       float* __restrict__ out) {
  extern __shared__ char smem[];          // [0, 75776): W 128 rows x 37 chunks (592 B)
  float* part = (float*)(smem + 75776);   // [75776, 77824): 4 x 128 f32 partials

  const uint32_t tid = threadIdx.x;
  const uint32_t wid = tid >> 6, lane = tid & 63u;
  const uint32_t n0 = blockIdx.x * ROWS;
  const uint32_t mb = blockIdx.x * MPB;

  // zero W pad d=286,287 per row (A pad must be real zeros: 0*garbage may be NaN)
  if (tid < ROWS) *(uint32_t*)(smem + tid * RSTRB + 572u) = 0u;

  // ---- W-gen: element m = mb+p, p in [0,36608); w[row][d], row=p/286, d=p%286.
  // 8-wide vectorized fast path except at row/monomial boundaries (~3% of groups).
  for (uint32_t g = 0; g < 9u; ++g) {
    uint32_t t8 = g * 512u + tid;
    if (t8 >= 4576u) break;
    uint32_t p0 = t8 * 8u;
    uint32_t m0 = mb + p0;
    uint32_t row0 = p0 / 286u;
    uint32_t d0 = p0 - row0 * 286u;  // even
    bool slow = (d0 > 278u) || ((m0 >> NLOG) != ((m0 + 7u) >> NLOG));
    if (!slow) {
      uint32_t i = m0 >> NLOG, j0 = m0 & NMASK;  // j0 multiple of 8 -> aligned float4
      uint32_t tv = g_tab.v[i];
      float pr[8];
      int a = (int)(tv & 15u) - 1;
      if (a >= 0) {
        const float4* xa = (const float4*)(x + ((uint32_t)a << NLOG) + j0);
        float4 lo = xa[0], hi = xa[1];
        pr[0] = lo.x; pr[1] = lo.y; pr[2] = lo.z; pr[3] = lo.w;
        pr[4] = hi.x; pr[5] = hi.y; pr[6] = hi.z; pr[7] = hi.w;
        int b = (int)((tv >> 4) & 15u) - 1;
        if (b >= 0) {
          const float4* xb = (const float4*)(x + ((uint32_t)b << NLOG) + j0);
          float4 lo2 = xb[0], hi2 = xb[1];
          pr[0] *= lo2.x; pr[1] *= lo2.y; pr[2] *= lo2.z; pr[3] *= lo2.w;
          pr[4] *= hi2.x; pr[5] *= hi2.y; pr[6] *= hi2.z; pr[7] *= hi2.w;
          int c = (int)(tv >> 8) - 1;
          if (c >= 0) {
            const float4* xc = (const float4*)(x + ((uint32_t)c << NLOG) + j0);
            float4 lo3 = xc[0], hi3 = xc[1];
            pr[0] *= lo3.x; pr[1] *= lo3.y; pr[2] *= lo3.z; pr[3] *= lo3.w;
            pr[4] *= hi3.x; pr[5] *= hi3.y; pr[6] *= hi3.z; pr[7] *= hi3.w;
          }
        }
      } else {
#pragma unroll
        for (int u = 0; u < 8; ++u) pr[u] = 1.f;
      }
#pragma unroll
      for (uint32_t u = 0; u < 4u; ++u) {
        uint32_t d = d0 + 2u * u;
        *(uint32_t*)(smem + row0 * RSTRB + d * 2u) = pk2bf(pr[2 * u], pr[2 * u + 1]);
      }
    } else {
#pragma unroll
      for (uint32_t u = 0; u < 8u; ++u) {
        uint32_t p = p0 + u, m = m0 + u;
        uint32_t i = m >> NLOG, j = m & NMASK;
        uint32_t tv = g_tab.v[i];
        float val = 1.f;
        int a = (int)(tv & 15u) - 1;
        if (a >= 0) {
          val = x[((uint32_t)a << NLOG) + j];
          int b = (int)((tv >> 4) & 15u) - 1;
          if (b >= 0) {
            val *= x[((uint32_t)b << NLOG) + j];
            int c = (int)(tv >> 8) - 1;
            if (c >= 0) val *= x[((uint32_t)c << NLOG) + j];
          }
        }
        uint32_t row = p / 286u, d = p - row * 286u;
        *(uint16_t*)(smem + row * RSTRB + d * 2u) = (uint16_t)f2bf(val);
      }
    }
  }

  // ---- GEMM: wave (wr,we): rows wr*64..+64 (rf=4), e-cols we*80..+80 (fe=5).
  // A from LDS (stride-37 conflict-free), B from global (L2-resident), single-buffered:
  // b[5] loaded per k-step, one a-fragment live at a time (keeps live set < 128).
  const uint32_t wr = wid >> 2, we = wid & 3u;
  const uint32_t ag = lane >> 4;   // k-octet group
  const uint32_t al = lane & 15u;  // row-in-frag / col-in-frag
  const uint4* bbase = g_bpack + ag * 320u + we * 80u + al;
  const char* arow = smem + (wr * 64u + al) * RSTRB;

  short8 b[5];
#pragma unroll
  for (uint32_t fe = 0; fe < 5u; ++fe) b[fe] = *(const short8*)(bbase + fe * 16u);

  f32x4 acc[4][5];
#pragma unroll
  for (int rf = 0; rf < 4; ++rf)
#pragma unroll
    for (int fe = 0; fe < 5; ++fe) acc[rf][fe] = (f32x4){0.f, 0.f, 0.f, 0.f};

  __syncthreads();

  // k0 = 0 (b preloaded before the barrier)
#pragma unroll
  for (uint32_t rf = 0; rf < 4u; ++rf) {
    short8 a = *(const short8*)(arow + rf * 16u * RSTRB + ag * 16u);
#pragma unroll
    for (int fe = 0; fe < 5; ++fe)
      acc[rf][fe] = __builtin_amdgcn_mfma_f32_16x16x32_bf16(a, b[fe], acc[rf][fe], 0, 0, 0);
  }
#pragma unroll 1
  for (uint32_t k0 = 1; k0 < 9u; ++k0) {
#pragma unroll
    for (uint32_t fe = 0; fe < 5u; ++fe)
      b[fe] = *(const short8*)(bbase + k0 * 1280u + fe * 16u);
#pragma unroll
    for (uint32_t rf = 0; rf < 4u; ++rf) {
      short8 a = *(const short8*)(arow + rf * 16u * RSTRB + (k0 * 4u + ag) * 16u);
#pragma unroll
      for (int fe = 0; fe < 5; ++fe)
        acc[rf][fe] = __builtin_amdgcn_mfma_f32_16x16x32_bf16(a, b[fe], acc[rf][fe], 0, 0, 0);
    }
  }

  // ---- epilogue: C-frag rows r=wr*64+rf*16+ag*4+i, col e=we*80+fe*16+al; dot with w-row.
  // CLAMP e<288: acc==0 for e>=286 (B cols zeroed) but LDS past d=287 is garbage (0*NaN=NaN).
  float rs[4][4];
#pragma unroll
  for (uint32_t rf = 0; rf < 4u; ++rf) {
#pragma unroll
    for (uint32_t i = 0; i < 4u; ++i) {
      uint32_t r = wr * 64u + rf * 16u + ag * 4u + i;
      float s = 0.f;
#pragma unroll
      for (uint32_t fe = 0; fe < 5u; ++fe) {
        uint32_t e = we * 80u + fe * 16u + al;
        float wv = (e < 288u)
            ? bf2f(*(const uint16_t*)(smem + r * RSTRB + e * 2u))
            : 0.f;
        s = fmaf(acc[rf][fe][i], wv, s);
      }
      rs[rf][i] = s;
    }
  }
#pragma unroll
  for (uint32_t rf = 0; rf < 4u; ++rf)
#pragma unroll
    for (uint32_t i = 0; i < 4u; ++i) {
      float s = rs[rf][i];
      s += __shfl_xor(s, 1); s += __shfl_xor(s, 2);
      s += __shfl_xor(s, 4); s += __shfl_xor(s, 8);
      rs[rf][i] = s;
    }
  if (al == 0u) {
#pragma unroll
    for (uint32_t rf = 0; rf < 4u; ++rf)
#pragma unroll
      for (uint32_t i = 0; i < 4u; ++i)
        part[we * 128u + wr * 64u + rf * 16u + ag * 4u + i] = rs[rf][i];
  }
  __syncthreads();
  if (tid < ROWS) {
    out[n0 + tid] = part[tid] + part[128u + tid] + part[256u + tid] + part[384u + tid];
  }
}

extern "C" void kernel_launch(void* const* d_in, const int* in_sizes, int n_in,
                              void* d_out, int out_size, void* d_ws, size_t ws_size,
                              hipStream_t stream) {
  const float* x = (const float*)d_in[0];   // 262144*10 fp32, viewed as xr[10][262144]
  const float* M = (const float*)d_in[1];   // 286*286 fp32
  float* out = (float*)d_out;               // 262144 fp32
  (void)in_sizes; (void)n_in; (void)out_size; (void)d_ws; (void)ws_size;
  prep_kernel<<<45, 256, 0, stream>>>(M);
  hipFuncSetAttribute((const void*)qform_kernel, hipFuncAttributeMaxDynamicSharedMemorySize,
                      77824);
  qform_kernel<<<2048, 512, 77824, stream>>>(x, out);
}

// Round 12
// 177.313 us; speedup vs baseline: 1.8182x; 1.8182x over previous
//
#include <hip/hip_runtime.h>
#include <hip/hip_bf16.h>
#include <stdint.h>

#define NLOG 18
#define NMASK ((1u << NLOG) - 1u)
#define RSTRB 592u  // W row stride bytes = 37 chunks * 16; 148 dwords == 20 mod 32 banks
#define ROWS 32u
#define TPB 384u    // 6 waves: we = wid in [0,6), each wave 32 rows x 48 e (6*48 = 288 exact)
#define MPB (ROWS * 286u)  // 9152 w-elements per block

typedef __attribute__((ext_vector_type(8))) short short8;
typedef __attribute__((ext_vector_type(4))) float f32x4;
typedef f32x4 uf32x4 __attribute__((aligned(4)));  // 4B-align-safe vector load (j0 may be ==2 mod 4)

// ---- compile-time monomial table: nibble-packed (a+1)|(b+1)<<4|(c+1)<<8 ----
struct Tab { uint16_t v[286]; };
constexpr Tab make_tab() {
  Tab t{};
  int idx = 0;
  t.v[idx++] = 0;  // degree 0
  for (int a = 0; a < 10; ++a) t.v[idx++] = (uint16_t)(a + 1);
  for (int a = 0; a < 10; ++a)
    for (int b = a; b < 10; ++b) t.v[idx++] = (uint16_t)((a + 1) | ((b + 1) << 4));
  for (int a = 0; a < 10; ++a)
    for (int b = a; b < 10; ++b)
      for (int c = b; c < 10; ++c)
        t.v[idx++] = (uint16_t)((a + 1) | ((b + 1) << 4) | ((c + 1) << 8));
  return t;
}
__constant__ Tab g_tab = make_tab();

// Packed bf16 B: 9 k-steps x 4 k-octets x 320 e; 16B chunk = M[k0*32+g*8+i][e], i=0..7.
// 184 KB, L2-resident -> read directly in the k-loop (register double-buffered).
__device__ uint4 g_bpack[11520];

__device__ __forceinline__ uint32_t f2bf(float f) {
  uint32_t u = __float_as_uint(f);
  return (u + 0x7FFFu + ((u >> 16) & 1u)) >> 16;
}
__device__ __forceinline__ float bf2f(uint32_t u) { return __uint_as_float(u << 16); }
__device__ __forceinline__ uint32_t pk2bf(float lo, float hi) {
  __hip_bfloat162 h2 = __float22bfloat162_rn(make_float2(lo, hi));  // v_cvt_pk_bf16_f32
  return *(uint32_t*)&h2;
}

__global__ __launch_bounds__(256) void prep_kernel(const float* __restrict__ M) {
  uint32_t t = blockIdx.x * 256u + threadIdx.x;  // 0..11519
  uint32_t k0 = t / 1280u;
  uint32_t r = t - k0 * 1280u;
  uint32_t g = r / 320u;
  uint32_t e = r - g * 320u;
  uint32_t kb = k0 * 32u + g * 8u;
  float v[8];
#pragma unroll
  for (int i = 0; i < 8; ++i) {
    uint32_t k = kb + (uint32_t)i;
    v[i] = (k < 286u && e < 286u) ? M[k * 286u + e] : 0.f;
  }
  uint4 o;
  o.x = f2bf(v[0]) | (f2bf(v[1]) << 16);
  o.y = f2bf(v[2]) | (f2bf(v[3]) << 16);
  o.z = f2bf(v[4]) | (f2bf(v[5]) << 16);
  o.w = f2bf(v[6]) | (f2bf(v[7]) << 16);
  g_bpack[t] = o;
}

__device__ __forceinline__ float mono1(const float* __restrict__ x, uint32_t tv, uint32_t j) {
  float val = 1.f;
  int a = (int)(tv & 15u) - 1;
  if (a >= 0) {
    val = x[((uint32_t)a << NLOG) + j];
    int b = (int)((tv >> 4) & 15u) - 1;
    if (b >= 0) {
      val *= x[((uint32_t)b << NLOG) + j];
      int c = (int)(tv >> 8) - 1;
      if (c >= 0) val *= x[((uint32_t)c << NLOG) + j];
    }
  }
  return val;
}

// Budget @ __launch_bounds__(384,6) -> 85-reg tier, 4 blocks/CU (24/32 waves = 75%):
// GEMM live: acc 24 (AGPR) + bA 12 + bB 12 + a 8 + addr ~12 ~= 70 < 85. Spill tell = WRITE_SIZE.
__global__ __launch_bounds__(TPB, 6) void qform_kernel(const float* __restrict__ x,
                                                       float* __restrict__ out) {
  extern __shared__ char smem[];          // [0, 18944): W 32 rows x 37 chunks (592 B stride)
  float* part = (float*)(smem + 18944);   // [18944, 19712): 6 x 32 f32 partials

  const uint32_t tid = threadIdx.x;
  const uint32_t wid = tid >> 6, lane = tid & 63u;
  const uint32_t n0 = blockIdx.x * ROWS;
  const uint32_t mb = blockIdx.x * MPB;

  // ---- W-gen main pass: uniform (row, grp) mapping, 4 elems/group, 71 groups cover d 0..283.
  // All groups are in-row -> no row-boundary divergence; only rare i-crossing takes slow path.
  for (uint32_t it = 0; it < 6u; ++it) {
    uint32_t t4 = it * TPB + tid;
    if (t4 >= 2272u) break;              // 32 rows * 71 groups
    uint32_t row = t4 / 71u;
    uint32_t grp = t4 - row * 71u;
    uint32_t d0 = grp * 4u;              // 0..280, covers d0..d0+3 <= 283
    uint32_t m0 = mb + row * 286u + d0;
    uint32_t i = m0 >> NLOG;
    if (__builtin_expect((m0 + 3u) >> NLOG == i, 1)) {
      uint32_t j0 = m0 & NMASK;          // j0 mod 4 in {0,2}: use 4B-aligned vector loads
      uint32_t tv = g_tab.v[i];
      float pr[4];
      int a = (int)(tv & 15u) - 1;
      if (a >= 0) {
        uf32x4 va = *(const uf32x4*)(x + ((uint32_t)a << NLOG) + j0);
        pr[0] = va.x; pr[1] = va.y; pr[2] = va.z; pr[3] = va.w;
        int b = (int)((tv >> 4) & 15u) - 1;
        if (b >= 0) {
          uf32x4 vb = *(const uf32x4*)(x + ((uint32_t)b << NLOG) + j0);
          pr[0] *= vb.x; pr[1] *= vb.y; pr[2] *= vb.z; pr[3] *= vb.w;
          int c = (int)(tv >> 8) - 1;
          if (c >= 0) {
            uf32x4 vc = *(const uf32x4*)(x + ((uint32_t)c << NLOG) + j0);
            pr[0] *= vc.x; pr[1] *= vc.y; pr[2] *= vc.z; pr[3] *= vc.w;
          }
        }
      } else {
        pr[0] = 1.f; pr[1] = 1.f; pr[2] = 1.f; pr[3] = 1.f;
      }
      uint2 w01;
      w01.x = pk2bf(pr[0], pr[1]);
      w01.y = pk2bf(pr[2], pr[3]);
      *(uint2*)(smem + row * RSTRB + d0 * 2u) = w01;  // d0*2 % 8 == 0 -> ds_write_b64
    } else {
      // i-crossing group (<= 1 per ~14 blocks): per-element scalar
#pragma unroll
      for (uint32_t u = 0; u < 4u; ++u) {
        uint32_t m = m0 + u;
        float val = mono1(x, g_tab.v[m >> NLOG], m & NMASK);
        *(uint16_t*)(smem + row * RSTRB + (d0 + u) * 2u) = (uint16_t)f2bf(val);
      }
    }
  }
  // ---- tail pass: d=284,285 real monomials; d=286,287 zero pad (one thread per row)
  if (tid < ROWS) {
    uint32_t row = tid;
#pragma unroll
    for (uint32_t u = 0; u < 2u; ++u) {
      uint32_t m = mb + row * 286u + 284u + u;
      float val = mono1(x, g_tab.v[m >> NLOG], m & NMASK);
      *(uint16_t*)(smem + row * RSTRB + (284u + u) * 2u) = (uint16_t)f2bf(val);
    }
    *(uint32_t*)(smem + row * RSTRB + 572u) = 0u;  // d = 286, 287
  }

  // ---- GEMM: wave we = wid: rows 0..31 (rf=2), e-cols we*48..+48 (fe=3).
  // A from LDS (stride-37 conflict-free), B from global (L2-resident), depth-1
  // register double-buffer (bA current, bB next; bA reload targets k0+2).
  const uint32_t we = wid;
  const uint32_t ag = lane >> 4;   // k-octet group
  const uint32_t al = lane & 15u;  // row-in-frag / col-in-frag
  const uint4* bbase = g_bpack + ag * 320u + we * 48u + al;
  const char* arow0 = smem + al * RSTRB;
  const char* arow1 = smem + (16u + al) * RSTRB;

  short8 bA[3];
#pragma unroll
  for (uint32_t fe = 0; fe < 3u; ++fe) bA[fe] = *(const short8*)(bbase + fe * 16u);

  f32x4 acc[2][3];
#pragma unroll
  for (int rf = 0; rf < 2; ++rf)
#pragma unroll
    for (int fe = 0; fe < 3; ++fe) acc[rf][fe] = (f32x4){0.f, 0.f, 0.f, 0.f};

  __syncthreads();

#pragma unroll 1
  for (uint32_t kp = 0; kp < 4u; ++kp) {
    const uint32_t k0 = 2u * kp;
    short8 bB[3];
#pragma unroll
    for (uint32_t fe = 0; fe < 3u; ++fe)
      bB[fe] = *(const short8*)(bbase + (k0 + 1u) * 1280u + fe * 16u);
    {
      short8 a0 = *(const short8*)(arow0 + (k0 * 4u + ag) * 16u);
      short8 a1 = *(const short8*)(arow1 + (k0 * 4u + ag) * 16u);
#pragma unroll
      for (int fe = 0; fe < 3; ++fe) {
        acc[0][fe] = __builtin_amdgcn_mfma_f32_16x16x32_bf16(a0, bA[fe], acc[0][fe], 0, 0, 0);
        acc[1][fe] = __builtin_amdgcn_mfma_f32_16x16x32_bf16(a1, bA[fe], acc[1][fe], 0, 0, 0);
      }
    }
#pragma unroll
    for (uint32_t fe = 0; fe < 3u; ++fe)
      bA[fe] = *(const short8*)(bbase + (k0 + 2u) * 1280u + fe * 16u);
    {
      short8 a0 = *(const short8*)(arow0 + ((k0 + 1u) * 4u + ag) * 16u);
      short8 a1 = *(const short8*)(arow1 + ((k0 + 1u) * 4u + ag) * 16u);
#pragma unroll
      for (int fe = 0; fe < 3; ++fe) {
        acc[0][fe] = __builtin_amdgcn_mfma_f32_16x16x32_bf16(a0, bB[fe], acc[0][fe], 0, 0, 0);
        acc[1][fe] = __builtin_amdgcn_mfma_f32_16x16x32_bf16(a1, bB[fe], acc[1][fe], 0, 0, 0);
      }
    }
  }
  {  // k0 = 8 (bA holds k=8 from the last iteration)
    short8 a0 = *(const short8*)(arow0 + (32u + ag) * 16u);
    short8 a1 = *(const short8*)(arow1 + (32u + ag) * 16u);
#pragma unroll
    for (int fe = 0; fe < 3; ++fe) {
      acc[0][fe] = __builtin_amdgcn_mfma_f32_16x16x32_bf16(a0, bA[fe], acc[0][fe], 0, 0, 0);
      acc[1][fe] = __builtin_amdgcn_mfma_f32_16x16x32_bf16(a1, bA[fe], acc[1][fe], 0, 0, 0);
    }
  }

  // ---- epilogue: C-frag row r=rf*16+ag*4+i, col e=we*48+fe*16+al (max 287 -> no clamp
  // needed; d 286,287 zeroed). Dot with w-row, reduce over al via shfl_xor(1,2,4,8).
  float rs[2][4];
#pragma unroll
  for (uint32_t rf = 0; rf < 2u; ++rf) {
#pragma unroll
    for (uint32_t i = 0; i < 4u; ++i) {
      uint32_t r = rf * 16u + ag * 4u + i;
      float s = 0.f;
#pragma unroll
      for (uint32_t fe = 0; fe < 3u; ++fe) {
        uint32_t e = we * 48u + fe * 16u + al;
        float wv = bf2f(*(const uint16_t*)(smem + r * RSTRB + e * 2u));
        s = fmaf(acc[rf][fe][i], wv, s);
      }
      rs[rf][i] = s;
    }
  }
#pragma unroll
  for (uint32_t rf = 0; rf < 2u; ++rf)
#pragma unroll
    for (uint32_t i = 0; i < 4u; ++i) {
      float s = rs[rf][i];
      s += __shfl_xor(s, 1); s += __shfl_xor(s, 2);
      s += __shfl_xor(s, 4); s += __shfl_xor(s, 8);
      rs[rf][i] = s;
    }
  if (al == 0u) {
#pragma unroll
    for (uint32_t rf = 0; rf < 2u; ++rf)
#pragma unroll
      for (uint32_t i = 0; i < 4u; ++i)
        part[we * 32u + rf * 16u + ag * 4u + i] = rs[rf][i];
  }
  __syncthreads();
  if (tid < ROWS) {
    float o = 0.f;
#pragma unroll
    for (uint32_t w = 0; w < 6u; ++w) o += part[w * 32u + tid];
    out[n0 + tid] = o;
  }
}

extern "C" void kernel_launch(void* const* d_in, const int* in_sizes, int n_in,
                              void* d_out, int out_size, void* d_ws, size_t ws_size,
                              hipStream_t stream) {
  const float* x = (const float*)d_in[0];   // 262144*10 fp32, viewed as xr[10][262144]
  const float* M = (const float*)d_in[1];   // 286*286 fp32
  float* out = (float*)d_out;               // 262144 fp32
  (void)in_sizes; (void)n_in; (void)out_size; (void)d_ws; (void)ws_size;
  prep_kernel<<<45, 256, 0, stream>>>(M);
  qform_kernel<<<8192, TPB, 19712, stream>>>(x, out);
}

// Round 14
// 163.973 us; speedup vs baseline: 1.9661x; 1.0814x over previous
//
#include <hip/hip_runtime.h>
#include <hip/hip_bf16.h>
#include <stdint.h>

#define NLOG 18
#define NMASK ((1u << NLOG) - 1u)
#define RSTRB 592u  // W row stride bytes = 37 chunks * 16; 148 dwords == 20 mod 32 banks
#define ROWS 32u
#define TPB 384u    // 6 waves: we = wid in [0,6), each wave 32 rows x 48 e (6*48 = 288 exact)
#define MPB (ROWS * 286u)  // 9152 w-elements per block

typedef __attribute__((ext_vector_type(8))) short short8;
typedef __attribute__((ext_vector_type(4))) float f32x4;
typedef f32x4 uf32x4 __attribute__((aligned(8)));  // j0 is even -> 8B-aligned vec4 loads

// ---- compile-time monomial table: nibble-packed (a+1)|(b+1)<<4|(c+1)<<8 ----
struct Tab { uint16_t v[286]; };
constexpr Tab make_tab() {
  Tab t{};
  int idx = 0;
  t.v[idx++] = 0;  // degree 0
  for (int a = 0; a < 10; ++a) t.v[idx++] = (uint16_t)(a + 1);
  for (int a = 0; a < 10; ++a)
    for (int b = a; b < 10; ++b) t.v[idx++] = (uint16_t)((a + 1) | ((b + 1) << 4));
  for (int a = 0; a < 10; ++a)
    for (int b = a; b < 10; ++b)
      for (int c = b; c < 10; ++c)
        t.v[idx++] = (uint16_t)((a + 1) | ((b + 1) << 4) | ((c + 1) << 8));
  return t;
}
__constant__ Tab g_tab = make_tab();

// Packed bf16 B: octet ko (0..35) x 320 e; 16B chunk = M[ko*8+i][e], i=0..7.
// 184 KB, L2-resident -> read directly in the k-loop (single-buffered; latency
// covered by 7 waves/SIMD TLP: 7 x ~39 cy issue > ~200 cy L2 latency).
__device__ uint4 g_bpack[11520];

__device__ __forceinline__ uint32_t f2bf(float f) {
  uint32_t u = __float_as_uint(f);
  return (u + 0x7FFFu + ((u >> 16) & 1u)) >> 16;
}
__device__ __forceinline__ float bf2f(uint32_t u) { return __uint_as_float(u << 16); }
__device__ __forceinline__ uint32_t pk2bf(float lo, float hi) {
  __hip_bfloat162 h2 = __float22bfloat162_rn(make_float2(lo, hi));  // v_cvt_pk_bf16_f32
  return *(uint32_t*)&h2;
}

__global__ __launch_bounds__(256) void prep_kernel(const float* __restrict__ M) {
  uint32_t t = blockIdx.x * 256u + threadIdx.x;  // 0..11519
  uint32_t k0 = t / 1280u;
  uint32_t r = t - k0 * 1280u;
  uint32_t g = r / 320u;
  uint32_t e = r - g * 320u;
  uint32_t kb = k0 * 32u + g * 8u;
  float v[8];
#pragma unroll
  for (int i = 0; i < 8; ++i) {
    uint32_t k = kb + (uint32_t)i;
    v[i] = (k < 286u && e < 286u) ? M[k * 286u + e] : 0.f;
  }
  uint4 o;
  o.x = f2bf(v[0]) | (f2bf(v[1]) << 16);
  o.y = f2bf(v[2]) | (f2bf(v[3]) << 16);
  o.z = f2bf(v[4]) | (f2bf(v[5]) << 16);
  o.w = f2bf(v[6]) | (f2bf(v[7]) << 16);
  g_bpack[t] = o;
}

__device__ __forceinline__ float mono1(const float* __restrict__ x, uint32_t tv, uint32_t j) {
  float val = 1.f;
  int a = (int)(tv & 15u) - 1;
  if (a >= 0) {
    val = x[((uint32_t)a << NLOG) + j];
    int b = (int)((tv >> 4) & 15u) - 1;
    if (b >= 0) {
      val *= x[((uint32_t)b << NLOG) + j];
      int c = (int)(tv >> 8) - 1;
      if (c >= 0) val *= x[((uint32_t)c << NLOG) + j];
    }
  }
  return val;
}

// Budget @ __launch_bounds__(384,7) -> 73-reg unified cap, target 7 waves/EU:
// GEMM live: acc 24 (AGPR) + b 12 + a 8 + addr ~15 ~= 68 < 73. Spill tell = WRITE_SIZE.
// (round-12 measured: ~80 unified regs -> 6.4 waves/EU -> 61% occupancy; this round
// drops the second B buffer to cross the 7-wave tier.)
__global__ __launch_bounds__(TPB, 7) void qform_kernel(const float* __restrict__ x,
                                                       float* __restrict__ out) {
  extern __shared__ char smem[];          // [0, 18944): W 32 rows x 37 chunks (592 B stride)
  float* part = (float*)(smem + 18944);   // [18944, 19712): 6 x 32 f32 partials

  const uint32_t tid = threadIdx.x;
  const uint32_t wid = tid >> 6, lane = tid & 63u;
  const uint32_t n0 = blockIdx.x * ROWS;
  const uint32_t mb = blockIdx.x * MPB;

  // ---- W-gen: 8-wide groups, 36/row, 32*36 = 1152 = 3*TPB exactly (no guard, no tail).
  // Group 35 covers d 280..287: d 284,285 real monomials, 286,287 zero pad (w4.w = 0).
  // Fast path requires (m0+7) in same monomial i (also guards x OOB at j-window edge).
#pragma unroll
  for (uint32_t it = 0; it < 3u; ++it) {
    uint32_t t4 = it * TPB + tid;        // 0..1151
    uint32_t row = t4 / 36u;             // magic-mul
    uint32_t grp = t4 - row * 36u;
    uint32_t d0 = grp * 8u;              // 0..280
    uint32_t m0 = mb + row * 286u + d0;
    uint32_t i = m0 >> NLOG;
    bool lastg = (grp == 35u);
    if (__builtin_expect((m0 + 7u) >> NLOG == i, 1)) {
      uint32_t j0 = m0 & NMASK;          // even -> 8B aligned
      uint32_t tv = g_tab.v[i];
      float pr[8];
      int a = (int)(tv & 15u) - 1;
      if (a >= 0) {
        const uf32x4* xa = (const uf32x4*)(x + ((uint32_t)a << NLOG) + j0);
        uf32x4 lo = xa[0], hi = xa[1];
        pr[0] = lo.x; pr[1] = lo.y; pr[2] = lo.z; pr[3] = lo.w;
        pr[4] = hi.x; pr[5] = hi.y; pr[6] = hi.z; pr[7] = hi.w;
        int b = (int)((tv >> 4) & 15u) - 1;
        if (b >= 0) {
          const uf32x4* xb = (const uf32x4*)(x + ((uint32_t)b << NLOG) + j0);
          uf32x4 lo2 = xb[0], hi2 = xb[1];
          pr[0] *= lo2.x; pr[1] *= lo2.y; pr[2] *= lo2.z; pr[3] *= lo2.w;
          pr[4] *= hi2.x; pr[5] *= hi2.y; pr[6] *= hi2.z; pr[7] *= hi2.w;
          int c = (int)(tv >> 8) - 1;
          if (c >= 0) {
            const uf32x4* xc = (const uf32x4*)(x + ((uint32_t)c << NLOG) + j0);
            uf32x4 lo3 = xc[0], hi3 = xc[1];
            pr[0] *= lo3.x; pr[1] *= lo3.y; pr[2] *= lo3.z; pr[3] *= lo3.w;
            pr[4] *= hi3.x; pr[5] *= hi3.y; pr[6] *= hi3.z; pr[7] *= hi3.w;
          }
        }
      } else {
#pragma unroll
        for (int u = 0; u < 8; ++u) pr[u] = 1.f;
      }
      uint4 w4;
      w4.x = pk2bf(pr[0], pr[1]);
      w4.y = pk2bf(pr[2], pr[3]);
      w4.z = pk2bf(pr[4], pr[5]);
      w4.w = lastg ? 0u : pk2bf(pr[6], pr[7]);  // zero pad d=286,287
      *(uint4*)(smem + row * RSTRB + d0 * 2u) = w4;  // d0*2 % 16 == 0 -> ds_write_b128
    } else {
      // i-crossing group (~3.5% of blocks have one): per-element scalar
#pragma unroll
      for (uint32_t u = 0; u < 8u; ++u) {
        uint32_t d = d0 + u;
        uint32_t m = m0 + u;
        uint16_t hv = 0;
        if (d < 286u) hv = (uint16_t)f2bf(mono1(x, g_tab.v[m >> NLOG], m & NMASK));
        *(uint16_t*)(smem + row * RSTRB + d * 2u) = hv;
      }
    }
  }

  // ---- GEMM: wave we = wid: rows 0..31 (rf=2), e-cols we*48..+48 (fe=3).
  // A from LDS (stride-37 conflict-free), B from global (L2-resident), single-buffered.
  const uint32_t we = wid;
  const uint32_t ag = lane >> 4;   // k-octet group
  const uint32_t al = lane & 15u;  // row-in-frag / col-in-frag
  const uint4* bbase = g_bpack + ag * 320u + we * 48u + al;
  const char* arow0 = smem + al * RSTRB;
  const char* arow1 = smem + (16u + al) * RSTRB;

  short8 b[3];
#pragma unroll
  for (uint32_t fe = 0; fe < 3u; ++fe) b[fe] = *(const short8*)(bbase + fe * 16u);

  f32x4 acc[2][3];
#pragma unroll
  for (int rf = 0; rf < 2; ++rf)
#pragma unroll
    for (int fe = 0; fe < 3; ++fe) acc[rf][fe] = (f32x4){0.f, 0.f, 0.f, 0.f};

  __syncthreads();

  {  // k0 = 0 (b preloaded before the barrier)
    short8 a0 = *(const short8*)(arow0 + ag * 16u);
    short8 a1 = *(const short8*)(arow1 + ag * 16u);
#pragma unroll
    for (int fe = 0; fe < 3; ++fe) {
      acc[0][fe] = __builtin_amdgcn_mfma_f32_16x16x32_bf16(a0, b[fe], acc[0][fe], 0, 0, 0);
      acc[1][fe] = __builtin_amdgcn_mfma_f32_16x16x32_bf16(a1, b[fe], acc[1][fe], 0, 0, 0);
    }
  }
#pragma unroll 1
  for (uint32_t k0 = 1; k0 < 9u; ++k0) {
#pragma unroll
    for (uint32_t fe = 0; fe < 3u; ++fe)
      b[fe] = *(const short8*)(bbase + k0 * 1280u + fe * 16u);
    short8 a0 = *(const short8*)(arow0 + (k0 * 4u + ag) * 16u);
    short8 a1 = *(const short8*)(arow1 + (k0 * 4u + ag) * 16u);
#pragma unroll
    for (int fe = 0; fe < 3; ++fe) {
      acc[0][fe] = __builtin_amdgcn_mfma_f32_16x16x32_bf16(a0, b[fe], acc[0][fe], 0, 0, 0);
      acc[1][fe] = __builtin_amdgcn_mfma_f32_16x16x32_bf16(a1, b[fe], acc[1][fe], 0, 0, 0);
    }
  }

  // ---- epilogue: C-frag row r=rf*16+ag*4+i, col e=we*48+fe*16+al (max 287; d 286,287
  // zeroed so no clamp). Dot with w-row, reduce over al via shfl_xor(1,2,4,8).
  float rs[2][4];
#pragma unroll
  for (uint32_t rf = 0; rf < 2u; ++rf) {
#pragma unroll
    for (uint32_t i = 0; i < 4u; ++i) {
      uint32_t r = rf * 16u + ag * 4u + i;
      float s = 0.f;
#pragma unroll
      for (uint32_t fe = 0; fe < 3u; ++fe) {
        uint32_t e = we * 48u + fe * 16u + al;
        float wv = bf2f(*(const uint16_t*)(smem + r * RSTRB + e * 2u));
        s = fmaf(acc[rf][fe][i], wv, s);
      }
      rs[rf][i] = s;
    }
  }
#pragma unroll
  for (uint32_t rf = 0; rf < 2u; ++rf)
#pragma unroll
    for (uint32_t i = 0; i < 4u; ++i) {
      float s = rs[rf][i];
      s += __shfl_xor(s, 1); s += __shfl_xor(s, 2);
      s += __shfl_xor(s, 4); s += __shfl_xor(s, 8);
      rs[rf][i] = s;
    }
  if (al == 0u) {
#pragma unroll
    for (uint32_t rf = 0; rf < 2u; ++rf)
#pragma unroll
      for (uint32_t i = 0; i < 4u; ++i)
        part[we * 32u + rf * 16u + ag * 4u + i] = rs[rf][i];
  }
  __syncthreads();
  if (tid < ROWS) {
    float o = 0.f;
#pragma unroll
    for (uint32_t w = 0; w < 6u; ++w) o += part[w * 32u + tid];
    out[n0 + tid] = o;
  }
}

extern "C" void kernel_launch(void* const* d_in, const int* in_sizes, int n_in,
                              void* d_out, int out_size, void* d_ws, size_t ws_size,
                              hipStream_t stream) {
  const float* x = (const float*)d_in[0];   // 262144*10 fp32, viewed as xr[10][262144]
  const float* M = (const float*)d_in[1];   // 286*286 fp32
  float* out = (float*)d_out;               // 262144 fp32
  (void)in_sizes; (void)n_in; (void)out_size; (void)d_ws; (void)ws_size;
  prep_kernel<<<45, 256, 0, stream>>>(M);
  qform_kernel<<<8192, TPB, 19712, stream>>>(x, out);
}